// Round 4
// baseline (335.691 us; speedup 1.0000x reference)
//
#include <hip/hip_runtime.h>
#include <stdint.h>

typedef int v4i  __attribute__((ext_vector_type(4)));
typedef int v16i __attribute__((ext_vector_type(16)));

// direct global->LDS DMA, 16B per lane. LDS dest = wave-uniform base + lane*16.
__device__ __forceinline__ void gll16(const void* g, void* l) {
    __builtin_amdgcn_global_load_lds(
        (const __attribute__((address_space(1))) void*)(uintptr_t)g,
        (__attribute__((address_space(3))) void*)(uint32_t)(uintptr_t)l,
        16, 0, 0);
}

// ---------------- Kernel 1: per-row dynamic int8 quantization of x ----------------
__global__ __launch_bounds__(256) void quant_x(const float* __restrict__ x,
                                               signed char* __restrict__ xq,
                                               float* __restrict__ sx, int M) {
    const int row = blockIdx.x;
    const int tid = threadIdx.x;
    signed char* qrow = xq + (size_t)row * 1024;
    if (row >= M) {  // zero the pad rows (uniform branch per block)
        ((char4*)qrow)[tid] = make_char4(0, 0, 0, 0);
        if (tid == 0) sx[row] = 0.0f;
        return;
    }
    const float4 v = ((const float4*)(x + (size_t)row * 1024))[tid];
    float a = fmaxf(fmaxf(fabsf(v.x), fabsf(v.y)), fmaxf(fabsf(v.z), fabsf(v.w)));
#pragma unroll
    for (int off = 32; off > 0; off >>= 1)
        a = fmaxf(a, __shfl_xor(a, off));
    __shared__ float red[4];
    if ((tid & 63) == 0) red[tid >> 6] = a;
    __syncthreads();
    const float am = fmaxf(fmaxf(red[0], red[1]), fmaxf(red[2], red[3]));
    const float amc = fmaxf(am, 1e-8f);
    const float scale = amc * (1.0f / 127.0f);
    const float inv = 127.0f / amc;
    char4 q;
    q.x = (signed char)(int)rintf(v.x * inv);
    q.y = (signed char)(int)rintf(v.y * inv);
    q.z = (signed char)(int)rintf(v.z * inv);
    q.w = (signed char)(int)rintf(v.w * inv);
    ((char4*)qrow)[tid] = q;
    if (tid == 0) sx[row] = scale;
}

// ---------------- Kernel 2: w_int (int32, values in [-127,127]) -> int8 ----------------
__global__ __launch_bounds__(256) void conv_w(const int* __restrict__ w,
                                              signed char* __restrict__ w8, int n4) {
    const int i = blockIdx.x * 256 + threadIdx.x;
    if (i < n4) {
        const int4 v = ((const int4*)w)[i];
        char4 c;
        c.x = (signed char)v.x; c.y = (signed char)v.y;
        c.z = (signed char)v.z; c.w = (signed char)v.w;
        ((char4*)w8)[i] = c;
    }
}

// ---------------- Kernel 3: int8 GEMM, 256x256 tile, 4-phase, triple-buffered ----------------
// 8 waves (2M x 4N), wave tile 128x64 = 4m x 2n frags of 32x32, 2 k-steps -> 16
// MFMA (32x32x32 i8) per K-tile (BK=64 bytes). NT = K/64.
//
// LDS: THREE buffers of (A 16KB + B 16KB) = 96 KB. Tile T reads buf[T%3];
// stage(T+2) -> buf[(T+2)%3], which was last read in tile T-1 and fully retired at
// T-1's boundary (lgkm(0) + barrier). So staging issues at PHASE 0 of tile T and
// overlaps the entire tile's compute (~4 phases of MFMA >> HBM latency).
//
// Per tile: 4 phases {ds_read this phase's frags | stage-issue slice | setprio(1)
// 4 MFMA setprio(0) | s_barrier}. Counted s_waitcnt vmcnt(4) ONLY at the tile
// boundary (T+1's 4 DMAs retired; T+2's 4 still in flight) — never 0 mid-loop.
// Hazards: tile-T reads vs stage(T+2) are disjoint buffers; boundary lgkm(0)+
// barrier retires all waves' reads of buf[T%3] before any wave's stage(T+3)
// targets it in tile T+1; per-wave vmcnt + barrier makes all 8 waves' DMA slices
// collectively visible before the buffer is read.
//
// LDS XOR swizzle (verified): row r stores its four 16B K-chunks permuted by
// key=(r>>1)&3, applied on the GLOBAL fetch address (DMA cannot scatter);
// fragment reads un-swizzle with the same key -> uniform-minimum bank spread.
__global__ __launch_bounds__(512, 2) void gemm_i8(const signed char* __restrict__ xq,
                                                  const signed char* __restrict__ w8,
                                                  const float* __restrict__ sx,
                                                  const float* __restrict__ sw,
                                                  const float* __restrict__ bias,
                                                  float* __restrict__ out,
                                                  int M, int N, int K) {
    __shared__ signed char As[3][16384];   // 256 rows x 64B each
    __shared__ signed char Bs[3][16384];

    const int tid  = threadIdx.x;
    const int lane = tid & 63;
    const int wave = tid >> 6;
    const int m_off = (wave >> 2) * 128;   // 2 waves in M
    const int n_off = (wave & 3) * 64;     // 4 waves in N
    const int NT = K >> 6;

    // bijective XCD-aware block swizzle (m204): each XCD sweeps contiguous wgids.
    const int nwg = gridDim.x;
    const int qd = nwg >> 3, rd = nwg & 7;
    const int xcd = blockIdx.x & 7, lid = blockIdx.x >> 3;
    const int wgid = (xcd < rd ? xcd * (qd + 1) : rd * (qd + 1) + (xcd - rd) * qd) + lid;
    const int NXB = N >> 8;                // N / 256
    const int m_block = (wgid / NXB) * 256;
    const int n_block = (wgid % NXB) * 256;

    v16i acc[4][2];
#pragma unroll
    for (int mi = 0; mi < 4; ++mi)
#pragma unroll
        for (int ni = 0; ni < 2; ++ni)
#pragma unroll
            for (int e = 0; e < 16; ++e) acc[mi][ni][e] = 0;

    // staging map: thread t -> LDS slot (row t>>2 in 0..127, chunk t&3); fetches
    // swizzled global chunk (t&3)^((t>>3)&3). Key invariant under +128 rows.
    const int sr = tid >> 2;
    const int sc = ((tid & 3) ^ ((sr >> 1) & 3)) * 16;
    const signed char* aG = xq + (size_t)(m_block + sr) * K + sc;
    const signed char* bG = w8 + (size_t)(n_block + sr) * K + sc;
    const int ldst = wave * 1024;  // + lane*16 implicit in the DMA

    auto stageA = [&](int Tt, int b) {
        const size_t ko = (size_t)Tt << 6;
        gll16(aG + ko,                    &As[b][ldst]);
        gll16(aG + ko + ((size_t)K << 7), &As[b][ldst + 8192]);  // rows +128
    };
    auto stageB = [&](int Tt, int b) {
        const size_t ko = (size_t)Tt << 6;
        gll16(bG + ko,                    &Bs[b][ldst]);
        gll16(bG + ko + ((size_t)K << 7), &Bs[b][ldst + 8192]);
    };

    // 32x32x32 fragment read: lane l -> row (l&31), k-chunk ks*2+(l>>5), un-swizzled.
    const int rl  = lane & 31;
    const int hi  = lane >> 5;
    const int key = (rl >> 1) & 3;
    const int c0 = (hi ^ key) * 16;        // k-step 0 chunk byte offset
    const int c1 = ((2 + hi) ^ key) * 16;  // k-step 1
    const int arow = (m_off + rl) * 64;
    const int brow = (n_off + rl) * 64;

    // prologue: T0 -> buf0, T1 -> buf1; T0 resident, T1's 4 in flight
    stageA(0, 0); stageB(0, 0);
    stageA(1, 1); stageB(1, 1);
    asm volatile("s_waitcnt vmcnt(4)" ::: "memory");
    __builtin_amdgcn_s_barrier();

    int cur = 0;
    for (int T = 0; T < NT; ++T) {
        int nx2 = cur + 2; if (nx2 >= 3) nx2 -= 3;
        const bool pf = (T + 2 < NT);
        const signed char* Ac = As[cur];
        const signed char* Bc = Bs[cur];

        v4i b0, b1;
        // ---- phase 0: k-step 0, m-frags 0-1 (stage A of T+2 flies under it) ----
        if (pf) stageA(T + 2, nx2);
        {
            v4i A0 = *(const v4i*)(Ac + arow + c0);
            v4i A1 = *(const v4i*)(Ac + arow + 2048 + c0);
            b0 = *(const v4i*)(Bc + brow + c0);
            b1 = *(const v4i*)(Bc + brow + 2048 + c0);
            __builtin_amdgcn_s_setprio(1);
            acc[0][0] = __builtin_amdgcn_mfma_i32_32x32x32_i8(A0, b0, acc[0][0], 0, 0, 0);
            acc[0][1] = __builtin_amdgcn_mfma_i32_32x32x32_i8(A0, b1, acc[0][1], 0, 0, 0);
            acc[1][0] = __builtin_amdgcn_mfma_i32_32x32x32_i8(A1, b0, acc[1][0], 0, 0, 0);
            acc[1][1] = __builtin_amdgcn_mfma_i32_32x32x32_i8(A1, b1, acc[1][1], 0, 0, 0);
            __builtin_amdgcn_s_setprio(0);
        }
        __builtin_amdgcn_s_barrier();
        // ---- phase 1: k-step 0, m-frags 2-3 (stage B of T+2) ----
        if (pf) stageB(T + 2, nx2);
        {
            v4i A2 = *(const v4i*)(Ac + arow + 4096 + c0);
            v4i A3 = *(const v4i*)(Ac + arow + 6144 + c0);
            __builtin_amdgcn_s_setprio(1);
            acc[2][0] = __builtin_amdgcn_mfma_i32_32x32x32_i8(A2, b0, acc[2][0], 0, 0, 0);
            acc[2][1] = __builtin_amdgcn_mfma_i32_32x32x32_i8(A2, b1, acc[2][1], 0, 0, 0);
            acc[3][0] = __builtin_amdgcn_mfma_i32_32x32x32_i8(A3, b0, acc[3][0], 0, 0, 0);
            acc[3][1] = __builtin_amdgcn_mfma_i32_32x32x32_i8(A3, b1, acc[3][1], 0, 0, 0);
            __builtin_amdgcn_s_setprio(0);
        }
        __builtin_amdgcn_s_barrier();
        // ---- phase 2: k-step 1, m-frags 0-1 ----
        {
            v4i A0 = *(const v4i*)(Ac + arow + c1);
            v4i A1 = *(const v4i*)(Ac + arow + 2048 + c1);
            b0 = *(const v4i*)(Bc + brow + c1);
            b1 = *(const v4i*)(Bc + brow + 2048 + c1);
            __builtin_amdgcn_s_setprio(1);
            acc[0][0] = __builtin_amdgcn_mfma_i32_32x32x32_i8(A0, b0, acc[0][0], 0, 0, 0);
            acc[0][1] = __builtin_amdgcn_mfma_i32_32x32x32_i8(A0, b1, acc[0][1], 0, 0, 0);
            acc[1][0] = __builtin_amdgcn_mfma_i32_32x32x32_i8(A1, b0, acc[1][0], 0, 0, 0);
            acc[1][1] = __builtin_amdgcn_mfma_i32_32x32x32_i8(A1, b1, acc[1][1], 0, 0, 0);
            __builtin_amdgcn_s_setprio(0);
        }
        __builtin_amdgcn_s_barrier();
        // ---- phase 3: k-step 1, m-frags 2-3, then tile boundary ----
        {
            v4i A2 = *(const v4i*)(Ac + arow + 4096 + c1);
            v4i A3 = *(const v4i*)(Ac + arow + 6144 + c1);
            __builtin_amdgcn_s_setprio(1);
            acc[2][0] = __builtin_amdgcn_mfma_i32_32x32x32_i8(A2, b0, acc[2][0], 0, 0, 0);
            acc[2][1] = __builtin_amdgcn_mfma_i32_32x32x32_i8(A2, b1, acc[2][1], 0, 0, 0);
            acc[3][0] = __builtin_amdgcn_mfma_i32_32x32x32_i8(A3, b0, acc[3][0], 0, 0, 0);
            acc[3][1] = __builtin_amdgcn_mfma_i32_32x32x32_i8(A3, b1, acc[3][1], 0, 0, 0);
            __builtin_amdgcn_s_setprio(0);
        }
        asm volatile("s_waitcnt lgkmcnt(0)" ::: "memory");  // all buf[cur] reads retired
        if (T + 1 < NT) {
            if (pf)
                asm volatile("s_waitcnt vmcnt(4)" ::: "memory");  // T+1 resident; T+2 in flight
            else
                asm volatile("s_waitcnt vmcnt(0)" ::: "memory");  // tail: nothing newer
            __builtin_amdgcn_s_barrier();                   // tile boundary
        }
        cur = (cur + 1 == 3) ? 0 : cur + 1;
    }

    // epilogue: 32x32 C/D layout: col = lane&31, row = (reg&3) + 8*(reg>>2) + 4*(lane>>5)
#pragma unroll
    for (int mi = 0; mi < 4; ++mi)
#pragma unroll
        for (int q = 0; q < 4; ++q) {
            const int rbase = m_block + m_off + mi * 32 + q * 8 + hi * 4;
            float sxv[4];
#pragma unroll
            for (int r = 0; r < 4; ++r) sxv[r] = sx[rbase + r];  // pad rows: sx=0
#pragma unroll
            for (int ni = 0; ni < 2; ++ni) {
                const int col = n_block + n_off + ni * 32 + rl;
                const float swv = sw[col];
                const float bv  = bias[col];
#pragma unroll
                for (int r = 0; r < 4; ++r) {
                    const int row = rbase + r;
                    if (row < M)
                        out[(size_t)row * N + col] = (float)acc[mi][ni][q * 4 + r] * sxv[r] * swv + bv;
                }
            }
        }
}

extern "C" void kernel_launch(void* const* d_in, const int* in_sizes, int n_in,
                              void* d_out, int out_size, void* d_ws, size_t ws_size,
                              hipStream_t stream) {
    const float* x       = (const float*)d_in[0];
    const int*   w_int   = (const int*)d_in[1];
    const float* scale_w = (const float*)d_in[2];
    const float* bias    = (const float*)d_in[3];
    float* out = (float*)d_out;

    const int D_OUT = in_sizes[2];             // 2560
    const int D_IN  = in_sizes[1] / D_OUT;     // 1024
    const int M     = in_sizes[0] / D_IN;      // 18464
    const int Mpad  = ((M + 255) / 256) * 256; // 18688

    // workspace layout (all 16B-aligned):
    signed char* xq = (signed char*)d_ws;                      // Mpad * D_IN  int8
    signed char* w8 = xq + (size_t)Mpad * D_IN;                // D_OUT * D_IN int8
    float*       sx = (float*)(w8 + (size_t)D_OUT * D_IN);     // Mpad floats

    quant_x<<<Mpad, 256, 0, stream>>>(x, xq, sx, M);
    const int n4 = D_OUT * D_IN / 4;
    conv_w<<<(n4 + 255) / 256, 256, 0, stream>>>(w_int, w8, n4);
    const int nwg = (D_OUT / 256) * (Mpad / 256);  // 10 x 73 = 730
    gemm_i8<<<dim3(nwg, 1, 1), dim3(512, 1, 1), 0, stream>>>(xq, w8, sx, scale_w, bias, out, M, D_OUT, D_IN);
}

// Round 6
// 325.684 us; speedup vs baseline: 1.0307x; 1.0307x over previous
//
#include <hip/hip_runtime.h>
#include <stdint.h>

typedef int v4i  __attribute__((ext_vector_type(4)));
typedef int v16i __attribute__((ext_vector_type(16)));

// direct global->LDS DMA, 16B per lane. LDS dest = wave-uniform base + lane*16.
__device__ __forceinline__ void gll16(const void* g, void* l) {
    __builtin_amdgcn_global_load_lds(
        (const __attribute__((address_space(1))) void*)(uintptr_t)g,
        (__attribute__((address_space(3))) void*)(uint32_t)(uintptr_t)l,
        16, 0, 0);
}

// ---------------- Kernel 1: per-row dynamic int8 quantization of x ----------------
__global__ __launch_bounds__(256) void quant_x(const float* __restrict__ x,
                                               signed char* __restrict__ xq,
                                               float* __restrict__ sx, int M) {
    const int row = blockIdx.x;
    const int tid = threadIdx.x;
    signed char* qrow = xq + (size_t)row * 1024;
    if (row >= M) {  // zero the pad rows (uniform branch per block)
        ((char4*)qrow)[tid] = make_char4(0, 0, 0, 0);
        if (tid == 0) sx[row] = 0.0f;
        return;
    }
    const float4 v = ((const float4*)(x + (size_t)row * 1024))[tid];
    float a = fmaxf(fmaxf(fabsf(v.x), fabsf(v.y)), fmaxf(fabsf(v.z), fabsf(v.w)));
#pragma unroll
    for (int off = 32; off > 0; off >>= 1)
        a = fmaxf(a, __shfl_xor(a, off));
    __shared__ float red[4];
    if ((tid & 63) == 0) red[tid >> 6] = a;
    __syncthreads();
    const float am = fmaxf(fmaxf(red[0], red[1]), fmaxf(red[2], red[3]));
    const float amc = fmaxf(am, 1e-8f);
    const float scale = amc * (1.0f / 127.0f);
    const float inv = 127.0f / amc;
    char4 q;
    q.x = (signed char)(int)rintf(v.x * inv);
    q.y = (signed char)(int)rintf(v.y * inv);
    q.z = (signed char)(int)rintf(v.z * inv);
    q.w = (signed char)(int)rintf(v.w * inv);
    ((char4*)qrow)[tid] = q;
    if (tid == 0) sx[row] = scale;
}

// ---------------- Kernel 2: w_int (int32, values in [-127,127]) -> int8 ----------------
__global__ __launch_bounds__(256) void conv_w(const int* __restrict__ w,
                                              signed char* __restrict__ w8, int n4) {
    const int i = blockIdx.x * 256 + threadIdx.x;
    if (i < n4) {
        const int4 v = ((const int4*)w)[i];
        char4 c;
        c.x = (signed char)v.x; c.y = (signed char)v.y;
        c.z = (signed char)v.z; c.w = (signed char)v.w;
        ((char4*)w8)[i] = c;
    }
}

// ---------------- Kernel 3: int8 GEMM, 128x128 tile, triple-buffered, 1 barrier/tile ----------------
// 4 waves, each owns a 64x64 output subtile = 2x2 grid of 32x32x32 i8 MFMAs,
// 2 k-steps per K-tile (BK=64 bytes), NT = K/64 = 16.
//
// LDS: THREE buffers of (A 8KB + B 8KB) = 48 KB -> still 3 blocks/CU (the R4
// lesson: never trade occupancy for pipeline depth at this shape). Tile T reads
// buf[T%3]; stage(T+2) targets buf[(T+2)%3], which was fully retired at T-1's
// boundary (lgkm(0)+barrier there). So staging issues at TILE START and overlaps
// the entire tile's compute, and each tile needs only ONE barrier:
//   { stage(T+2) | ds_read ks1 | MFMA ks0 | MFMA ks1 } lgkm(0) vmcnt(4) barrier
//   { ds_read ks0 of T+1 ... }
// The explicit lgkm(0) before the barrier is load-bearing: it retires this wave's
// ds_reads of buf[cur] even if the compiler sinks the consuming MFMAs past the
// barrier (asm "memory" clobber orders memory ops, not MFMAs) — without it a fast
// wave's stage(T+3) in tile T+1 could overwrite buf[cur] under a slow wave's
// in-flight read. Counted vmcnt(4) at the boundary (T+1's 4 DMAs retired, T+2's
// 4 in flight) — never 0 mid-loop.
//
// LDS XOR swizzle (verified): row r stores its four 16B K-chunks permuted by
// key=(r>>1)&3, applied on the GLOBAL fetch address (DMA cannot scatter);
// fragment reads un-swizzle with the same key -> uniform-minimum bank spread.
__global__ __launch_bounds__(256, 3) void gemm_i8(const signed char* __restrict__ xq,
                                                  const signed char* __restrict__ w8,
                                                  const float* __restrict__ sx,
                                                  const float* __restrict__ sw,
                                                  const float* __restrict__ bias,
                                                  float* __restrict__ out,
                                                  int M, int N, int K) {
    __shared__ signed char As[3][8192];   // 128 rows x 64B each
    __shared__ signed char Bs[3][8192];

    const int tid  = threadIdx.x;
    const int lane = tid & 63;
    const int wave = tid >> 6;
    const int m_off = (wave >> 1) * 64;
    const int n_off = (wave & 1) * 64;
    const int NT = K >> 6;

    // bijective XCD-aware block swizzle (m204): each XCD sweeps contiguous wgids,
    // so the ~20 blocks sharing one A-panel hit the same XCD's L2.
    const int nwg = gridDim.x;
    const int qd = nwg >> 3, rd = nwg & 7;
    const int xcd = blockIdx.x & 7, lid = blockIdx.x >> 3;
    const int wgid = (xcd < rd ? xcd * (qd + 1) : rd * (qd + 1) + (xcd - rd) * qd) + lid;
    const int NXB = N >> 7;                // N / 128 = 20
    const int m_block = (wgid / NXB) * 128;
    const int n_block = (wgid % NXB) * 128;

    v16i acc[2][2];
#pragma unroll
    for (int mi = 0; mi < 2; ++mi)
#pragma unroll
        for (int ni = 0; ni < 2; ++ni)
#pragma unroll
            for (int e = 0; e < 16; ++e) acc[mi][ni][e] = 0;

    // staging map: thread t -> LDS slot (row t>>2, chunk t&3); fetches swizzled
    // global chunk (t&3)^((t>>3)&3). Key invariant under +64 rows.
    const int sr = tid >> 2;
    const int sc = ((tid & 3) ^ ((sr >> 1) & 3)) * 16;
    const signed char* aG = xq + (size_t)(m_block + sr) * K + sc;
    const signed char* bG = w8 + (size_t)(n_block + sr) * K + sc;
    const int ldst = wave * 1024;  // + lane*16 implicit in the DMA

    auto stage = [&](int Tt, int b) {
        const size_t ko = (size_t)Tt << 6;
        gll16(aG + ko,                    &As[b][ldst]);
        gll16(aG + ko + ((size_t)K << 6), &As[b][ldst + 4096]);  // rows +64
        gll16(bG + ko,                    &Bs[b][ldst]);
        gll16(bG + ko + ((size_t)K << 6), &Bs[b][ldst + 4096]);
    };

    // 32x32x32 fragment read: lane l -> row (l&31), k-chunk ks*2+(l>>5), un-swizzled.
    const int rl  = lane & 31;
    const int hi  = lane >> 5;
    const int key = (rl >> 1) & 3;
    const int c0 = (hi ^ key) * 16;        // k-step 0 chunk byte offset
    const int c1 = ((2 + hi) ^ key) * 16;  // k-step 1
    const int arow = (m_off + rl) * 64;
    const int brow = (n_off + rl) * 64;

    // prologue: T0 -> buf0, T1 -> buf1; T0 resident, T1's 4 in flight
    stage(0, 0);
    stage(1, 1);
    asm volatile("s_waitcnt vmcnt(4)" ::: "memory");
    __builtin_amdgcn_s_barrier();

    v4i a0, a1, b0, b1;      // k-step-0 fragments (preloaded at boundary)
    v4i na0, na1, nb0, nb1;  // k-step-1 fragments
    a0 = *(const v4i*)(As[0] + arow + c0);
    a1 = *(const v4i*)(As[0] + arow + 2048 + c0);
    b0 = *(const v4i*)(Bs[0] + brow + c0);
    b1 = *(const v4i*)(Bs[0] + brow + 2048 + c0);

    int cur = 0;
    for (int T = 0; T < NT; ++T) {
        int nxt = cur + 1; if (nxt >= 3) nxt -= 3;
        int nx2 = cur + 2; if (nx2 >= 3) nx2 -= 3;
        const bool pf = (T + 2 < NT);

        if (pf) stage(T + 2, nx2);   // flies under this whole tile's compute

        const signed char* Ac = As[cur];
        const signed char* Bc = Bs[cur];
        na0 = *(const v4i*)(Ac + arow + c1);
        na1 = *(const v4i*)(Ac + arow + 2048 + c1);
        nb0 = *(const v4i*)(Bc + brow + c1);
        nb1 = *(const v4i*)(Bc + brow + 2048 + c1);

        __builtin_amdgcn_s_setprio(1);
        acc[0][0] = __builtin_amdgcn_mfma_i32_32x32x32_i8(a0, b0, acc[0][0], 0, 0, 0);
        acc[0][1] = __builtin_amdgcn_mfma_i32_32x32x32_i8(a0, b1, acc[0][1], 0, 0, 0);
        acc[1][0] = __builtin_amdgcn_mfma_i32_32x32x32_i8(a1, b0, acc[1][0], 0, 0, 0);
        acc[1][1] = __builtin_amdgcn_mfma_i32_32x32x32_i8(a1, b1, acc[1][1], 0, 0, 0);
        __builtin_amdgcn_s_setprio(0);

        __builtin_amdgcn_s_setprio(1);
        acc[0][0] = __builtin_amdgcn_mfma_i32_32x32x32_i8(na0, nb0, acc[0][0], 0, 0, 0);
        acc[0][1] = __builtin_amdgcn_mfma_i32_32x32x32_i8(na0, nb1, acc[0][1], 0, 0, 0);
        acc[1][0] = __builtin_amdgcn_mfma_i32_32x32x32_i8(na1, nb0, acc[1][0], 0, 0, 0);
        acc[1][1] = __builtin_amdgcn_mfma_i32_32x32x32_i8(na1, nb1, acc[1][1], 0, 0, 0);
        __builtin_amdgcn_s_setprio(0);

        asm volatile("s_waitcnt lgkmcnt(0)" ::: "memory");  // my buf[cur] reads retired
        if (T + 1 < NT) {
            if (pf)
                asm volatile("s_waitcnt vmcnt(4)" ::: "memory");  // T+1 resident; T+2 in flight
            else
                asm volatile("s_waitcnt vmcnt(0)" ::: "memory");  // tail: nothing newer
            __builtin_amdgcn_s_barrier();                   // single boundary barrier
            const signed char* An = As[nxt];
            const signed char* Bn = Bs[nxt];
            a0 = *(const v4i*)(An + arow + c0);
            a1 = *(const v4i*)(An + arow + 2048 + c0);
            b0 = *(const v4i*)(Bn + brow + c0);
            b1 = *(const v4i*)(Bn + brow + 2048 + c0);
        }
        cur = nxt;
    }

    // epilogue: 32x32 C/D layout: col = lane&31, row = (reg&3) + 8*(reg>>2) + 4*(lane>>5)
#pragma unroll
    for (int mi = 0; mi < 2; ++mi)
#pragma unroll
        for (int q = 0; q < 4; ++q) {
            const int rbase = m_block + m_off + mi * 32 + q * 8 + hi * 4;
            float sxv[4];
#pragma unroll
            for (int r = 0; r < 4; ++r) sxv[r] = sx[rbase + r];  // pad rows: sx=0
#pragma unroll
            for (int ni = 0; ni < 2; ++ni) {
                const int col = n_block + n_off + ni * 32 + rl;
                const float swv = sw[col];
                const float bv  = bias[col];
#pragma unroll
                for (int r = 0; r < 4; ++r) {
                    const int row = rbase + r;
                    if (row < M)
                        out[(size_t)row * N + col] = (float)acc[mi][ni][q * 4 + r] * sxv[r] * swv + bv;
                }
            }
        }
}

extern "C" void kernel_launch(void* const* d_in, const int* in_sizes, int n_in,
                              void* d_out, int out_size, void* d_ws, size_t ws_size,
                              hipStream_t stream) {
    const float* x       = (const float*)d_in[0];
    const int*   w_int   = (const int*)d_in[1];
    const float* scale_w = (const float*)d_in[2];
    const float* bias    = (const float*)d_in[3];
    float* out = (float*)d_out;

    const int D_OUT = in_sizes[2];             // 2560
    const int D_IN  = in_sizes[1] / D_OUT;     // 1024
    const int M     = in_sizes[0] / D_IN;      // 18464
    const int Mpad  = ((M + 127) / 128) * 128; // 18560

    // workspace layout (all 16B-aligned):
    signed char* xq = (signed char*)d_ws;                      // Mpad * D_IN  int8
    signed char* w8 = xq + (size_t)Mpad * D_IN;                // D_OUT * D_IN int8
    float*       sx = (float*)(w8 + (size_t)D_OUT * D_IN);     // Mpad floats

    quant_x<<<Mpad, 256, 0, stream>>>(x, xq, sx, M);
    const int n4 = D_OUT * D_IN / 4;
    conv_w<<<(n4 + 255) / 256, 256, 0, stream>>>(w_int, w8, n4);
    const int nwg = (Mpad / 128) * (D_OUT / 128);  // 145 x 20 = 2900
    gemm_i8<<<dim3(nwg, 1, 1), dim3(256, 1, 1), 0, stream>>>(xq, w8, sx, scale_w, bias, out, M, D_OUT, D_IN);
}

// Round 7
// 317.498 us; speedup vs baseline: 1.0573x; 1.0258x over previous
//
#include <hip/hip_runtime.h>
#include <stdint.h>

typedef int v4i  __attribute__((ext_vector_type(4)));
typedef int v16i __attribute__((ext_vector_type(16)));

// direct global->LDS DMA, 16B per lane. LDS dest = wave-uniform base + lane*16.
__device__ __forceinline__ void gll16(const void* g, void* l) {
    __builtin_amdgcn_global_load_lds(
        (const __attribute__((address_space(1))) void*)(uintptr_t)g,
        (__attribute__((address_space(3))) void*)(uint32_t)(uintptr_t)l,
        16, 0, 0);
}

// ---------------- Kernel 1: per-row dynamic int8 quantization of x ----------------
__global__ __launch_bounds__(256) void quant_x(const float* __restrict__ x,
                                               signed char* __restrict__ xq,
                                               float* __restrict__ sx, int M) {
    const int row = blockIdx.x;
    const int tid = threadIdx.x;
    signed char* qrow = xq + (size_t)row * 1024;
    if (row >= M) {  // zero the pad rows (uniform branch per block)
        ((char4*)qrow)[tid] = make_char4(0, 0, 0, 0);
        if (tid == 0) sx[row] = 0.0f;
        return;
    }
    const float4 v = ((const float4*)(x + (size_t)row * 1024))[tid];
    float a = fmaxf(fmaxf(fabsf(v.x), fabsf(v.y)), fmaxf(fabsf(v.z), fabsf(v.w)));
#pragma unroll
    for (int off = 32; off > 0; off >>= 1)
        a = fmaxf(a, __shfl_xor(a, off));
    __shared__ float red[4];
    if ((tid & 63) == 0) red[tid >> 6] = a;
    __syncthreads();
    const float am = fmaxf(fmaxf(red[0], red[1]), fmaxf(red[2], red[3]));
    const float amc = fmaxf(am, 1e-8f);
    const float scale = amc * (1.0f / 127.0f);
    const float inv = 127.0f / amc;
    char4 q;
    q.x = (signed char)(int)rintf(v.x * inv);
    q.y = (signed char)(int)rintf(v.y * inv);
    q.z = (signed char)(int)rintf(v.z * inv);
    q.w = (signed char)(int)rintf(v.w * inv);
    ((char4*)qrow)[tid] = q;
    if (tid == 0) sx[row] = scale;
}

// ---------------- Kernel 2: w_int (int32, values in [-127,127]) -> int8 ----------------
__global__ __launch_bounds__(256) void conv_w(const int* __restrict__ w,
                                              signed char* __restrict__ w8, int n4) {
    const int i = blockIdx.x * 256 + threadIdx.x;
    if (i < n4) {
        const int4 v = ((const int4*)w)[i];
        char4 c;
        c.x = (signed char)v.x; c.y = (signed char)v.y;
        c.z = (signed char)v.z; c.w = (signed char)v.w;
        ((char4*)w8)[i] = c;
    }
}

// ---------------- Kernel 3: int8 GEMM (R2 structure + XCD swizzle ONLY) ----------------
// 4 waves, each owns a 64x64 output subtile = 2x2 grid of 32x32x32 i8 MFMAs.
// BK = 64 bytes of K per tile (2 k-steps of 32), NT = K/64 = 16.
// Loop structure byte-identical to the best-measured R2 kernel (315.1 us):
//   { ds_read ks1 | MFMA ks0 } -> lgkm(0)+B1 -> stage(T+2) -> vmcnt(4)+B2 ->
//   { ds_read T+1 ks0 | MFMA ks1 }, double-buffered LDS (32 KB), 3 blocks/CU.
// The ONLY change vs R2: bijective XCD-aware remap of the block id (m204 formula),
// so the 20 blocks sharing one 131 KB A-panel land on ONE XCD's L2 instead of
// round-robining across 8 (cuts ~150 MB of L3->L2 A re-fill; shortens the
// staging path the per-tile vmcnt(4) waits on). Per-XCD working set:
// ~5 A-panels (630 KB) + full B (2.6 MB) < 4 MB L2.
__global__ __launch_bounds__(256, 3) void gemm_i8(const signed char* __restrict__ xq,
                                                  const signed char* __restrict__ w8,
                                                  const float* __restrict__ sx,
                                                  const float* __restrict__ sw,
                                                  const float* __restrict__ bias,
                                                  float* __restrict__ out,
                                                  int M, int N, int K) {
    __shared__ signed char As[2][8192];   // 128 rows x 64B
    __shared__ signed char Bs[2][8192];

    const int tid  = threadIdx.x;
    const int lane = tid & 63;
    const int wave = tid >> 6;
    const int m_off = (wave >> 1) * 64;
    const int n_off = (wave & 1) * 64;
    const int NT = K >> 6;

    // bijective XCD-aware swizzle (m204): nwg = 2900 = 8*362+4.
    const int NXB = N >> 7;                            // 20
    const int lin = blockIdx.y * gridDim.x + blockIdx.x;
    const int nwg = gridDim.x * gridDim.y;
    const int qd = nwg >> 3, rd = nwg & 7;
    const int xcd = lin & 7, lid = lin >> 3;
    const int wgid = (xcd < rd ? xcd * (qd + 1) : rd * (qd + 1) + (xcd - rd) * qd) + lid;
    const int m_block = (wgid / NXB) * 128;
    const int n_block = (wgid % NXB) * 128;

    v16i acc[2][2];
#pragma unroll
    for (int mi = 0; mi < 2; ++mi)
#pragma unroll
        for (int ni = 0; ni < 2; ++ni)
#pragma unroll
            for (int e = 0; e < 16; ++e) acc[mi][ni][e] = 0;

    // staging map: thread t -> LDS slot (row t>>2, chunk t&3); fetches swizzled
    // global chunk (t&3)^((t>>3)&3). Key invariant under +64 rows.
    const int sr = tid >> 2;
    const int sc = ((tid & 3) ^ ((sr >> 1) & 3)) * 16;
    const signed char* aG = xq + (size_t)(m_block + sr) * K + sc;
    const signed char* bG = w8 + (size_t)(n_block + sr) * K + sc;
    const int ldst = wave * 1024;  // + lane*16 implicit in the DMA

    auto stage = [&](int Tt, int b) {
        const size_t ko = (size_t)Tt << 6;
        gll16(aG + ko,                    &As[b][ldst]);
        gll16(aG + ko + ((size_t)K << 6), &As[b][ldst + 4096]);  // rows +64
        gll16(bG + ko,                    &Bs[b][ldst]);
        gll16(bG + ko + ((size_t)K << 6), &Bs[b][ldst + 4096]);
    };

    // 32x32x32 fragment read: lane l -> row (l&31), k-chunk ks*2+(l>>5), un-swizzled.
    const int rl  = lane & 31;
    const int hi  = lane >> 5;
    const int key = (rl >> 1) & 3;
    const int c0 = (hi ^ key) * 16;        // k-step 0 chunk byte offset
    const int c1 = ((2 + hi) ^ key) * 16;  // k-step 1
    const int arow = (m_off + rl) * 64;
    const int brow = (n_off + rl) * 64;

    // prologue: T0 -> buf0, T1 -> buf1; T0 resident, T1's 4 in flight
    stage(0, 0);
    stage(1, 1);
    asm volatile("s_waitcnt vmcnt(4)" ::: "memory");
    __builtin_amdgcn_s_barrier();

    v4i a0, a1, b0, b1;      // current k-step fragments
    v4i na0, na1, nb0, nb1;  // next k-step fragments
    a0 = *(const v4i*)(As[0] + arow + c0);
    a1 = *(const v4i*)(As[0] + arow + 2048 + c0);
    b0 = *(const v4i*)(Bs[0] + brow + c0);
    b1 = *(const v4i*)(Bs[0] + brow + 2048 + c0);

    for (int T = 0; T < NT; ++T) {
        const int cur = T & 1;
        const signed char* Ac = As[cur];
        const signed char* Bc = Bs[cur];
        // issue ks1 reads; they overlap the ks0 MFMAs below
        na0 = *(const v4i*)(Ac + arow + c1);
        na1 = *(const v4i*)(Ac + arow + 2048 + c1);
        nb0 = *(const v4i*)(Bc + brow + c1);
        nb1 = *(const v4i*)(Bc + brow + 2048 + c1);

        acc[0][0] = __builtin_amdgcn_mfma_i32_32x32x32_i8(a0, b0, acc[0][0], 0, 0, 0);
        acc[0][1] = __builtin_amdgcn_mfma_i32_32x32x32_i8(a0, b1, acc[0][1], 0, 0, 0);
        acc[1][0] = __builtin_amdgcn_mfma_i32_32x32x32_i8(a1, b0, acc[1][0], 0, 0, 0);
        acc[1][1] = __builtin_amdgcn_mfma_i32_32x32x32_i8(a1, b1, acc[1][1], 0, 0, 0);

        asm volatile("s_waitcnt lgkmcnt(0)" ::: "memory");  // all buf[cur] reads retired
        __builtin_amdgcn_s_barrier();                       // B1: safe to overwrite buf[cur]

        if (T + 2 < NT) stage(T + 2, cur);

        if (T + 1 < NT) {
            if (T + 2 < NT)
                asm volatile("s_waitcnt vmcnt(4)" ::: "memory");  // T+1 resident; T+2 in flight
            else
                asm volatile("s_waitcnt vmcnt(0)" ::: "memory");  // tail: nothing newer
            __builtin_amdgcn_s_barrier();                   // B2: T+1 LDS visible
            const signed char* An = As[cur ^ 1];
            const signed char* Bn = Bs[cur ^ 1];
            // issue T+1 ks0 reads; they overlap the ks1 MFMAs below
            a0 = *(const v4i*)(An + arow + c0);
            a1 = *(const v4i*)(An + arow + 2048 + c0);
            b0 = *(const v4i*)(Bn + brow + c0);
            b1 = *(const v4i*)(Bn + brow + 2048 + c0);
        }

        acc[0][0] = __builtin_amdgcn_mfma_i32_32x32x32_i8(na0, nb0, acc[0][0], 0, 0, 0);
        acc[0][1] = __builtin_amdgcn_mfma_i32_32x32x32_i8(na0, nb1, acc[0][1], 0, 0, 0);
        acc[1][0] = __builtin_amdgcn_mfma_i32_32x32x32_i8(na1, nb0, acc[1][0], 0, 0, 0);
        acc[1][1] = __builtin_amdgcn_mfma_i32_32x32x32_i8(na1, nb1, acc[1][1], 0, 0, 0);
    }

    // epilogue: 32x32 C/D layout: col = lane&31, row = (reg&3) + 8*(reg>>2) + 4*(lane>>5)
#pragma unroll
    for (int mi = 0; mi < 2; ++mi)
#pragma unroll
        for (int q = 0; q < 4; ++q) {
            const int rbase = m_block + m_off + mi * 32 + q * 8 + hi * 4;
            float sxv[4];
#pragma unroll
            for (int r = 0; r < 4; ++r) sxv[r] = sx[rbase + r];  // pad rows: sx=0
#pragma unroll
            for (int ni = 0; ni < 2; ++ni) {
                const int col = n_block + n_off + ni * 32 + rl;
                const float swv = sw[col];
                const float bv  = bias[col];
#pragma unroll
                for (int r = 0; r < 4; ++r) {
                    const int row = rbase + r;
                    if (row < M)
                        out[(size_t)row * N + col] = (float)acc[mi][ni][q * 4 + r] * sxv[r] * swv + bv;
                }
            }
        }
}

extern "C" void kernel_launch(void* const* d_in, const int* in_sizes, int n_in,
                              void* d_out, int out_size, void* d_ws, size_t ws_size,
                              hipStream_t stream) {
    const float* x       = (const float*)d_in[0];
    const int*   w_int   = (const int*)d_in[1];
    const float* scale_w = (const float*)d_in[2];
    const float* bias    = (const float*)d_in[3];
    float* out = (float*)d_out;

    const int D_OUT = in_sizes[2];             // 2560
    const int D_IN  = in_sizes[1] / D_OUT;     // 1024
    const int M     = in_sizes[0] / D_IN;      // 18464
    const int Mpad  = ((M + 127) / 128) * 128; // 18560

    // workspace layout (all 16B-aligned):
    signed char* xq = (signed char*)d_ws;                      // Mpad * D_IN  int8
    signed char* w8 = xq + (size_t)Mpad * D_IN;                // D_OUT * D_IN int8
    float*       sx = (float*)(w8 + (size_t)D_OUT * D_IN);     // Mpad floats

    quant_x<<<Mpad, 256, 0, stream>>>(x, xq, sx, M);
    const int n4 = D_OUT * D_IN / 4;
    conv_w<<<(n4 + 255) / 256, 256, 0, stream>>>(w_int, w8, n4);
    dim3 grid(D_OUT / 128, Mpad / 128);  // 20 x 145 = 2900 blocks
    gemm_i8<<<grid, dim3(256, 1, 1), 0, stream>>>(xq, w8, sx, scale_w, bias, out, M, D_OUT, D_IN);
}